// Round 2
// baseline (240.600 us; speedup 1.0000x reference)
//
#include <hip/hip_runtime.h>
#include <hip/hip_bf16.h>
#include <stdint.h>

// B=32768, D=1024, T=8, O=128, DEPTH=6 -> 512 padded node cols (8 trees x 64)
#define KDIM 1024
#define TSTR 72            // tree stride in s/mu LDS tile (shorts): 144 B, 16B-aligned, bank-spread
#define RSTR 576           // row stride = 8*TSTR (shorts)

typedef __attribute__((ext_vector_type(4))) float f32x4;
typedef __attribute__((ext_vector_type(8))) short bf16x8;

// ws layout: wb [32 ks][512 n][32 kl] bf16 = 1 MiB @0 ; lb [16 kq][128 o][32] bf16 = 128 KiB @1 MiB
// total ws use: 1.125 MiB (R1's 33.6 MiB s-buffer removed -> no possible ws overflow)
#define WS_LB_OFF ((size_t)1 << 20)

__device__ __forceinline__ unsigned short f2bf_rne(float f) {
    unsigned u = __float_as_uint(f);
    u = (u + 0x7fffu + ((u >> 16) & 1u)) >> 16;
    return (unsigned short)u;
}

__device__ __forceinline__ unsigned int pack2_bf16(float a, float b) {
    __hip_bfloat162 h = __float22bfloat162_rn(make_float2(a, b));
    union { __hip_bfloat162 h; unsigned int u; } cv;
    cv.h = h;
    return cv.u;   // a in low 16 bits, b in high
}

// extract bf16 element i (0..63) from 8 packed uint4s; i is constant after unroll
__device__ __forceinline__ float gs_get(const uint4* q, int i) {
    uint4 v = q[i >> 3];
    int c = (i >> 1) & 3;
    unsigned w = (c == 0) ? v.x : (c == 1) ? v.y : (c == 2) ? v.z : v.w;
    return __uint_as_float((i & 1) ? (w & 0xffff0000u) : (w << 16));
}

// ---- prep: node weights -> bf16, layout [ks][n][32] with chunk swizzle cp^(n&3) ----
__global__ void prep_w(const float* __restrict__ nw, unsigned short* __restrict__ wb) {
    int idx = blockIdx.x * 256 + threadIdx.x;       // 524288 total
    int kl = idx & 31;
    int n  = (idx >> 5) & 511;
    int ks = idx >> 14;
    int cp = kl >> 3, e = kl & 7;
    int kchunk = cp ^ (n & 3);
    int d = ks * 32 + kchunk * 8 + e;
    int t = n >> 6, i = n & 63;
    float v = (i < 63) ? nw[(t * KDIM + d) * 63 + i] : 0.0f;
    wb[idx] = f2bf_rne(v);
}

// ---- prep: leaf weights -> bf16 [kq][o][32] ----
__global__ void prep_l(const float* __restrict__ lw, unsigned short* __restrict__ lb) {
    int idx = blockIdx.x * 256 + threadIdx.x;       // 65536 total
    int kk = idx & 31;
    int o  = (idx >> 5) & 127;
    int kq = idx >> 12;
    int c = kq * 32 + kk;                           // flattened leaf col: t*64 + l
    int t = c >> 6, l = c & 63;
    lb[idx] = f2bf_rne(lw[(t * 128 + o) * 64 + l]);
}

// ---- fused: s = smooth_step(x@W) [MFMA] -> tree scan -> out = mu@L [MFMA] ----
// block: 64 rows x 512 cols, K=1024, BK=32. 4 waves, each 64 rows x 128 cols.
__launch_bounds__(256, 2)
__global__ void fused(const float* __restrict__ x, const unsigned short* __restrict__ wb,
                      const unsigned short* __restrict__ lb, float* __restrict__ out) {
    __shared__ union __align__(16) {
        struct {
            unsigned short xs[64 * 40];    // x tile bf16, +8 pad (2-way-free banks)
            unsigned short wl[512 * 32];   // W tile (global_load_lds, swizzled chunks)
        } k;                               // 37,888 B
        unsigned short st[32 * RSTR];      // s/mu tile for one 32-row phase: 36,864 B
    } sm;

    const int tid  = threadIdx.x;
    const int wave = tid >> 6, lane = tid & 63;
    const int quad = lane >> 4, l16 = lane & 15;
    const int mb   = blockIdx.x;           // 512 blocks x 64 rows

    f32x4 acc[8][4];                       // [ct: col tile][rt: row tile]
    const f32x4 z4 = {0.f, 0.f, 0.f, 0.f};
    #pragma unroll
    for (int a = 0; a < 8; ++a)
        #pragma unroll
        for (int b = 0; b < 4; ++b) acc[a][b] = z4;

    const int xrow = tid >> 2, xq = tid & 3;
    const float* xg0 = x + (size_t)(mb * 64 + xrow) * KDIM + xq * 8;

    for (int ks = 0; ks < 32; ++ks) {
        __syncthreads();
        // stage W: 32 KB via global_load_lds (16 B/lane x 8 issues)
        const unsigned short* wks = wb + (size_t)ks * (512 * 32);
        #pragma unroll
        for (int it = 0; it < 8; ++it) {
            const unsigned short* gp = wks + (size_t)(it * 256 + tid) * 8;
            __builtin_amdgcn_global_load_lds(
                (const __attribute__((address_space(1))) unsigned int*)gp,
                (__attribute__((address_space(3))) unsigned int*)&sm.k.wl[(it * 256 + wave * 64) * 8],
                16, 0, 0);
        }
        // stage x: 8 fp32 -> 8 bf16 -> 1 ds_write_b128 per thread
        {
            const float4* xg = (const float4*)(xg0 + ks * 32);
            float4 f0 = xg[0], f1 = xg[1];
            uint4 p;
            p.x = pack2_bf16(f0.x, f0.y); p.y = pack2_bf16(f0.z, f0.w);
            p.z = pack2_bf16(f1.x, f1.y); p.w = pack2_bf16(f1.z, f1.w);
            *(uint4*)&sm.k.xs[xrow * 40 + xq * 8] = p;
        }
        __syncthreads();
        // fragments + 32 MFMA
        bf16x8 af[8], bf[4];
        #pragma unroll
        for (int ct = 0; ct < 8; ++ct) {
            int col = wave * 128 + ct * 16 + l16;
            int chunk = quad ^ (col & 3);
            af[ct] = *(const bf16x8*)&sm.k.wl[col * 32 + chunk * 8];
        }
        #pragma unroll
        for (int rt = 0; rt < 4; ++rt)
            bf[rt] = *(const bf16x8*)&sm.k.xs[(rt * 16 + l16) * 40 + quad * 8];
        #pragma unroll
        for (int ct = 0; ct < 8; ++ct)
            #pragma unroll
            for (int rt = 0; rt < 4; ++rt)
                acc[ct][rt] = __builtin_amdgcn_mfma_f32_16x16x32_bf16(af[ct], bf[rt], acc[ct][rt], 0, 0, 0);
    }

    // two 32-row phases: epilogue(s->LDS) -> scan(mu in place) -> GEMM2 -> out
    #pragma unroll
    for (int p = 0; p < 2; ++p) {
        __syncthreads();   // prior LDS readers (k-loop / gemm2 p=0) done
        // epilogue: smooth_step, write s bf16 into st (tree-strided layout)
        #pragma unroll
        for (int rt2 = 0; rt2 < 2; ++rt2) {
            int rowl = rt2 * 16 + l16;                    // phase-local row 0..31
            #pragma unroll
            for (int ct = 0; ct < 8; ++ct) {
                int colb = wave * 128 + ct * 16 + quad * 4;
                f32x4 a = acc[ct][p * 2 + rt2];
                float s0[4];
                #pragma unroll
                for (int j = 0; j < 4; ++j) {
                    float u = a[j];
                    u = fminf(fmaxf(u, -0.5f), 0.5f);     // cubic(+-.5) = 1/0 exactly
                    s0[j] = u * (1.5f - 2.0f * u * u) + 0.5f;
                }
                uint2 pk;
                pk.x = pack2_bf16(s0[0], s0[1]);
                pk.y = pack2_bf16(s0[2], s0[3]);
                *(uint2*)&sm.st[rowl * RSTR + (colb >> 6) * TSTR + (colb & 63)] = pk;
            }
        }
        __syncthreads();
        // scan: one (row, tree) per thread, in place s -> mu
        {
            int r = tid >> 3, t = tid & 7;
            unsigned short* base = &sm.st[r * RSTR + t * TSTR];
            uint4 q[8];
            #pragma unroll
            for (int c = 0; c < 8; ++c) q[c] = *(const uint4*)(base + c * 8);
            float mu[32];
            mu[0] = 1.0f;
            int start = 0;
            #pragma unroll
            for (int lvl = 0; lvl < 5; ++lvl) {           // levels 0..4 in-register
                int width = 1 << lvl;
                #pragma unroll
                for (int j = width - 1; j >= 0; --j) {
                    float m = mu[j], s_ = gs_get(q, start + j);
                    mu[2 * j + 1] = m * (1.0f - s_);
                    mu[2 * j]     = m * s_;
                }
                start += width;
            }
            #pragma unroll
            for (int c = 0; c < 8; ++c) {                 // level 5 fused with pack+store
                unsigned pk2[4];
                #pragma unroll
                for (int e = 0; e < 4; ++e) {
                    int j = c * 4 + e;
                    float m = mu[j], s_ = gs_get(q, 31 + j);
                    pk2[e] = pack2_bf16(m * s_, m * (1.0f - s_));
                }
                uint4 v; v.x = pk2[0]; v.y = pk2[1]; v.z = pk2[2]; v.w = pk2[3];
                *(uint4*)(base + c * 8) = v;
            }
        }
        __syncthreads();
        // GEMM2: A = leaf (global, L2-hot), B = mu (LDS). wave -> (row tile, o half)
        {
            int rtile = wave & 1, ob = (wave >> 1) * 64;
            f32x4 a2[4];
            a2[0] = z4; a2[1] = z4; a2[2] = z4; a2[3] = z4;
            #pragma unroll
            for (int kq = 0; kq < 16; ++kq) {
                int c0 = kq * 32 + quad * 8;
                bf16x8 bmu = *(const bf16x8*)&sm.st[(rtile * 16 + l16) * RSTR + (c0 >> 6) * TSTR + (c0 & 63)];
                #pragma unroll
                for (int ct = 0; ct < 4; ++ct) {
                    int o = ob + ct * 16 + l16;
                    bf16x8 alf = *(const bf16x8*)(lb + (size_t)(kq * 128 + o) * 32 + quad * 8);
                    a2[ct] = __builtin_amdgcn_mfma_f32_16x16x32_bf16(alf, bmu, a2[ct], 0, 0, 0);
                }
            }
            #pragma unroll
            for (int ct = 0; ct < 4; ++ct) {
                int rowg = mb * 64 + p * 32 + rtile * 16 + l16;
                int og = ob + ct * 16 + quad * 4;
                *(f32x4*)(out + (size_t)rowg * 128 + og) = a2[ct];
            }
        }
    }
}

extern "C" void kernel_launch(void* const* d_in, const int* in_sizes, int n_in,
                              void* d_out, int out_size, void* d_ws, size_t ws_size,
                              hipStream_t stream) {
    const float* x  = (const float*)d_in[0];
    const float* nw = (const float*)d_in[1];
    const float* lw = (const float*)d_in[2];
    float* out = (float*)d_out;

    unsigned short* wb = (unsigned short*)d_ws;
    unsigned short* lb = (unsigned short*)((char*)d_ws + WS_LB_OFF);

    prep_w<<<2048, 256, 0, stream>>>(nw, wb);
    prep_l<<<256, 256, 0, stream>>>(lw, lb);
    fused<<<512, 256, 0, stream>>>(x, wb, lb, out);
}